// Round 2
// baseline (169.748 us; speedup 1.0000x reference)
//
#include <hip/hip_runtime.h>
#include <hip/hip_bf16.h>

// out[b,p,:] = sequence[b, positions[b,p], :]
// B=8, S=4096, H=1024, P=512. Pure row gather: 16 MiB read + 16 MiB write.
// 4 rows per block, 256 threads; thread i copies float4 #i of each row
// (H/4 = 256 float4 per row). 4 independent gathers in flight per thread.
// Stores are non-temporal: out is write-once, keep L2/L3 for seq.

// Native clang vector type — __builtin_nontemporal_store rejects the
// HIP_vector_type<float,4> class, but accepts ext_vector_type.
using nfloat4 = __attribute__((ext_vector_type(4))) float;

__global__ void __launch_bounds__(256)
onehot_gather_kernel(const float* __restrict__ seq,
                     const int* __restrict__ pos,
                     float* __restrict__ out) {
    constexpr int S = 4096, H = 1024, P = 512;
    constexpr int RPB = 4;                       // rows per block
    const int row0 = blockIdx.x * RPB;
    const int i = threadIdx.x;                   // float4 index within row

    // row0 % 4 == 0 -> 16B-aligned: one vector load for all 4 indices.
    const int4 sidx = *reinterpret_cast<const int4*>(pos + row0);
    const int s[RPB] = {sidx.x, sidx.y, sidx.z, sidx.w};

    nfloat4 v[RPB];
#pragma unroll
    for (int r = 0; r < RPB; ++r) {
        const int row = row0 + r;
        const int b = row >> 9;                  // row / P, P = 512
        const nfloat4* __restrict__ src =
            reinterpret_cast<const nfloat4*>(seq + ((size_t)b * S + (size_t)s[r]) * H);
        v[r] = src[i];
    }
#pragma unroll
    for (int r = 0; r < RPB; ++r) {
        nfloat4* __restrict__ dst =
            reinterpret_cast<nfloat4*>(out + (size_t)(row0 + r) * H);
        __builtin_nontemporal_store(v[r], dst + i);
    }
}

extern "C" void kernel_launch(void* const* d_in, const int* in_sizes, int n_in,
                              void* d_out, int out_size, void* d_ws, size_t ws_size,
                              hipStream_t stream) {
    const float* seq = (const float*)d_in[0];   // [B, S, H] fp32
    const int*   pos = (const int*)d_in[1];     // [B, P] int32
    float*       out = (float*)d_out;           // [B, P, H] fp32

    constexpr int B = 8, P = 512, RPB = 4;
    dim3 grid((B * P) / RPB);                    // 1024 blocks
    dim3 block(256);
    onehot_gather_kernel<<<grid, block, 0, stream>>>(seq, pos, out);
}

// Round 3
// 169.274 us; speedup vs baseline: 1.0028x; 1.0028x over previous
//
#include <hip/hip_runtime.h>
#include <hip/hip_bf16.h>

// out[b,p,:] = sequence[b, positions[b,p], :]
// B=8, S=4096, H=1024, P=512. Pure row gather: 16 MiB read + 16 MiB write.
// 4 rows per block, 256 threads; thread i copies float4 #i of each row
// (H/4 = 256 float4 per row). 4 independent gathers in flight per thread.
//
// NOTE (R2 post-mortem): the bench's timed region is dominated by the
// harness's reset() poison fills (2 x 512 MiB at ~80 us each, themselves at
// 82-84% of HBM peak). This kernel's own dispatch is ~10 us. NT stores were
// reverted: out (16 MiB) fits in L2, and forcing the write drain to HBM
// costs ~+1-2 us at dispatch retire.
__global__ void __launch_bounds__(256)
onehot_gather_kernel(const float* __restrict__ seq,
                     const int* __restrict__ pos,
                     float* __restrict__ out) {
    constexpr int S = 4096, H = 1024, P = 512;
    constexpr int RPB = 4;                       // rows per block
    const int row0 = blockIdx.x * RPB;
    const int i = threadIdx.x;                   // float4 index within row

    // row0 % 4 == 0 -> 16B-aligned: one vector load for all 4 indices.
    const int4 sidx = *reinterpret_cast<const int4*>(pos + row0);
    const int s[RPB] = {sidx.x, sidx.y, sidx.z, sidx.w};

    float4 v[RPB];
#pragma unroll
    for (int r = 0; r < RPB; ++r) {
        const int row = row0 + r;
        const int b = row >> 9;                  // row / P, P = 512
        const float4* __restrict__ src =
            reinterpret_cast<const float4*>(seq + ((size_t)b * S + (size_t)s[r]) * H);
        v[r] = src[i];
    }
#pragma unroll
    for (int r = 0; r < RPB; ++r) {
        float4* __restrict__ dst =
            reinterpret_cast<float4*>(out + (size_t)(row0 + r) * H);
        dst[i] = v[r];
    }
}

extern "C" void kernel_launch(void* const* d_in, const int* in_sizes, int n_in,
                              void* d_out, int out_size, void* d_ws, size_t ws_size,
                              hipStream_t stream) {
    const float* seq = (const float*)d_in[0];   // [B, S, H] fp32
    const int*   pos = (const int*)d_in[1];     // [B, P] int32
    float*       out = (float*)d_out;           // [B, P, H] fp32

    constexpr int B = 8, P = 512, RPB = 4;
    dim3 grid((B * P) / RPB);                    // 1024 blocks
    dim3 block(256);
    onehot_gather_kernel<<<grid, block, 0, stream>>>(seq, pos, out);
}